// Round 5
// baseline (360.636 us; speedup 1.0000x reference)
//
#include <hip/hip_runtime.h>
#include <hip/hip_cooperative_groups.h>

namespace cg = cooperative_groups;

#define N_NODES 100000
#define N_EDGES 800000
#define IN_SIZE 128
#define OUT_SIZE 64

#define RP_CHUNKS   ((N_EDGES + 255) / 256)   // 3125 edge chunks (rowptr)
#define N_TILES     (N_NODES / 16)            // 6250 exact
#define PROP_CHUNKS ((N_NODES + 63) / 64)     // 1563 node chunks, 64/chunk
#define WS 136   // Wt LDS stride in bf16 elements (272B rows, 16B-aligned)

typedef __attribute__((ext_vector_type(8))) short short8;
typedef __attribute__((ext_vector_type(4))) float f32x4;

__device__ __forceinline__ unsigned short f2bf(float x) {
    unsigned u = __float_as_uint(x);
    u += 0x7FFFu + ((u >> 16) & 1u);          // round-to-nearest-even
    return (unsigned short)(u >> 16);
}
__device__ __forceinline__ unsigned pack2(float lo, float hi) {
    return (unsigned)f2bf(lo) | ((unsigned)f2bf(hi) << 16);
}

// int8 row layout (both H buffers): row = 16 dwords; dword d's byte b holds
// channel (d + 16*b), stored BIASED (u = q + 128). Per-row fp32 dequant
// scale in a separate array: val = scale * (u - 128).

#define ACC16(vv, c)                                                        \
    {                                                                        \
        const unsigned* _w = (const unsigned*)&(vv);                         \
        _Pragma("unroll")                                                    \
        for (int _d = 0; _d < 4; ++_d) {                                     \
            _Pragma("unroll")                                                \
            for (int _b = 0; _b < 4; ++_b)                                   \
                acc[_d * 4 + _b] = fmaf(                                     \
                    (float)((_w[_d] >> (8 * _b)) & 255u), (c), acc[_d*4+_b]);\
        }                                                                    \
    }

// Shared memory: gemm phase (Wt + Clds) and final-unpermute phase (T) are
// separated by grid.sync(), so they can alias.
struct __align__(16) SMem {
    union {
        struct { unsigned short Wt[64 * WS]; unsigned Clds[4][16 * 20]; } g; // 22528 B
        float T[64 * 68];                                                    // 17408 B
    };
};

// ---------------------------------------------------------------------------
// Propagation phase body (shared by round 1 / round 2-final).
// Identical arithmetic to the 3-kernel version; blockIdx replaced by
// grid-stride chunk index nb.
// ---------------------------------------------------------------------------
template <bool FINAL>
__device__ __forceinline__ void prop_phase(
    const uint4* __restrict__ inq, const float* __restrict__ insc,
    uint4* __restrict__ outq, float* __restrict__ outsc,
    float* __restrict__ out, const int* __restrict__ rowptr,
    const int* __restrict__ src, float* __restrict__ T, int G)
{
    const int tid   = threadIdx.x;
    const int lane  = tid & 63;
    const int s     = lane & 3;     // 16B chunk (dwords s*4..s*4+3)
    const int lbase = lane & 60;    // subgroup base lane

    for (int nb = (int)blockIdx.x; nb < PROP_CHUNKS; nb += G) {
        const int noder = nb * 64 + (tid >> 2);
        const bool valid = noder < N_NODES;
        const int node  = valid ? noder : N_NODES - 1;

        const int start = rowptr[node];
        const int end   = rowptr[node + 1];
        const int deg   = end - start;

        float acc[16];
        #pragma unroll
        for (int k = 0; k < 16; ++k) acc[k] = 0.f;
        float sumS = 0.f;

        if (deg > 0) {
            {   // own contribution first: ownq/owns die before the edge loop
                const uint4 ownq = inq[(size_t)node * 4 + s];
                const float owns = insc[node];
                ACC16(ownq, owns);
                sumS = owns;
            }
            for (int base = start; base < end; base += 8) {
                const int rem = end - base;
                const int liA = base + s;
                const int svA = src[liA < end ? liA : base];
                int svB = 0;
                if (base + 4 < end) {
                    const int liB = base + 4 + s;
                    svB = src[liB < end ? liB : base + 4];
                }
                const int e0 = __shfl(svA, lbase + 0, 64);
                const int e1 = __shfl(svA, lbase + 1, 64);
                const int e2 = __shfl(svA, lbase + 2, 64);
                const int e3 = __shfl(svA, lbase + 3, 64);
                const int e4 = __shfl(svB, lbase + 0, 64);
                const int e5 = __shfl(svB, lbase + 1, 64);
                const int e6 = __shfl(svB, lbase + 2, 64);
                const int e7 = __shfl(svB, lbase + 3, 64);

                const int i1 = rem > 1 ? e1 : e0;
                const int i2 = rem > 2 ? e2 : e0;
                const int i3 = rem > 3 ? e3 : e0;
                const int i4 = rem > 4 ? e4 : e0;
                const int i5 = rem > 5 ? e5 : e0;
                const int i6 = rem > 6 ? e6 : e0;
                const int i7 = rem > 7 ? e7 : e0;

                const uint4 v0 = inq[(size_t)e0 * 4 + s];
                const uint4 v1 = inq[(size_t)i1 * 4 + s];
                const uint4 v2 = inq[(size_t)i2 * 4 + s];
                const uint4 v3 = inq[(size_t)i3 * 4 + s];
                const uint4 v4 = inq[(size_t)i4 * 4 + s];
                const uint4 v5 = inq[(size_t)i5 * 4 + s];
                const uint4 v6 = inq[(size_t)i6 * 4 + s];
                const uint4 v7 = inq[(size_t)i7 * 4 + s];

                const float c0 = insc[e0];
                const float c1 = rem > 1 ? insc[i1] : 0.f;
                const float c2 = rem > 2 ? insc[i2] : 0.f;
                const float c3 = rem > 3 ? insc[i3] : 0.f;
                const float c4 = rem > 4 ? insc[i4] : 0.f;
                const float c5 = rem > 5 ? insc[i5] : 0.f;
                const float c6 = rem > 6 ? insc[i6] : 0.f;
                const float c7 = rem > 7 ? insc[i7] : 0.f;

                sumS += (c0 + c1) + (c2 + c3) + ((c4 + c5) + (c6 + c7));
                ACC16(v0, c0); ACC16(v1, c1); ACC16(v2, c2); ACC16(v3, c3);
                ACC16(v4, c4); ACC16(v5, c5); ACC16(v6, c6); ACC16(v7, c7);
            }
        }

        float val[16];
        if (deg == 0) {
            #pragma unroll
            for (int k = 0; k < 16; ++k) val[k] = 0.f;
        } else {
            const float invm  = 1.0f / (float)(deg + 1);
            const float bias  = 128.f * sumS;
            #pragma unroll
            for (int k = 0; k < 16; ++k) {
                val[k] = (acc[k] - bias) * invm;
                if (FINAL) val[k] = fmaxf(val[k], 0.f);
            }
        }

        if (FINAL) {
            // un-permute: channel of val[d*4+b] is (s*4+d) + 16*b
            const int nl = tid >> 2;
            #pragma unroll
            for (int d = 0; d < 4; ++d)
                #pragma unroll
                for (int bb = 0; bb < 4; ++bb)
                    T[nl * 68 + (s * 4 + d) + 16 * bb] = val[d * 4 + bb];
            __syncthreads();
            const int nbase = nb * 64;
            #pragma unroll
            for (int p = 0; p < 4; ++p) {
                const int pos = p * 1024 + tid * 4;  // dword index in 64x64 tile
                const int n   = pos >> 6;
                const int ch  = pos & 63;
                if (nbase + n < N_NODES) {
                    const float4 vv = *(const float4*)(T + n * 68 + ch);
                    *(float4*)(out + (size_t)(nbase + n) * OUT_SIZE + ch) = vv;
                }
            }
            __syncthreads();   // T reused by next grid-stride iteration
        } else {
            // requantize: row absmax across 16 in-lane + 4-lane subgroup
            float m = 0.f;
            #pragma unroll
            for (int k = 0; k < 16; ++k) m = fmaxf(m, fabsf(val[k]));
            m = fmaxf(m, __shfl_xor(m, 1, 64));
            m = fmaxf(m, __shfl_xor(m, 2, 64));
            const float invq = m > 0.f ? 127.f / m : 0.f;
            uint4 pv;
            unsigned* pw = (unsigned*)&pv;
            #pragma unroll
            for (int d = 0; d < 4; ++d) {
                const unsigned u0 = (unsigned)(int)rintf(val[d * 4 + 0] * invq + 128.f);
                const unsigned u1 = (unsigned)(int)rintf(val[d * 4 + 1] * invq + 128.f);
                const unsigned u2 = (unsigned)(int)rintf(val[d * 4 + 2] * invq + 128.f);
                const unsigned u3 = (unsigned)(int)rintf(val[d * 4 + 3] * invq + 128.f);
                pw[d] = u0 | (u1 << 8) | (u2 << 16) | (u3 << 24);
            }
            if (valid) {
                outq[(size_t)node * 4 + s] = pv;
                if (s == 0) outsc[node] = m * (1.f / 127.f);
            }
        }
    }
}

// ---------------------------------------------------------------------------
// R13: single fused cooperative kernel.
//   phase 0: rowptr (grid-stride edge chunks) + H0 = q8(data@W+b) via MFMA
//   grid.sync
//   phase 1: prop round 1 -> H1 (requant)
//   grid.sync
//   phase 2: prop round 2 -> out (fp32, relu)
// Rationale: (a) removes ~15-20us of inter-kernel launch/drain gaps;
// (b) the whole pipeline becomes ONE dispatch > 42us, so it finally tops
// the rocprof table and we get real FETCH/VGPR/Occupancy for the hot code;
// (c) the barrier structure enables phased (src-range-split) gathering next.
// __launch_bounds__(256,4): VGPR<=128 -> 4 blocks/CU co-resident (grid is
// occupancy-clamped at launch; everything is grid-stride so any grid works).
// ---------------------------------------------------------------------------
__global__ __launch_bounds__(256, 4) void gcn_fused(
    const float* __restrict__ data, const float* __restrict__ W,
    const float* __restrict__ b, const int* __restrict__ src,
    const int* __restrict__ tgt,
    uint4* __restrict__ H0, float* __restrict__ H0s,
    uint4* __restrict__ H1, float* __restrict__ H1s,
    int* __restrict__ rowptr, float* __restrict__ out)
{
    cg::grid_group grid = cg::this_grid();
    const int G   = (int)gridDim.x;
    const int tid = (int)threadIdx.x;

    __shared__ SMem sm;

    // ---------------- phase 0a: rowptr boundary-detect scatter --------------
    for (int c = (int)blockIdx.x; c < RP_CHUNKS; c += G) {
        const int e = c * 256 + tid;
        if (e < N_EDGES) {
            const int bb = tgt[e];
            const int a  = (e == 0) ? -1 : tgt[e - 1];
            for (int t = a + 1; t <= bb; ++t) rowptr[t] = e;
            if (e == N_EDGES - 1)
                for (int t = bb + 1; t <= N_NODES; ++t) rowptr[t] = N_EDGES;
        }
    }

    // ---------------- phase 0b: stage W -> LDS bf16 transposed --------------
    {
        const int p = tid & 63;
        const int h = tid >> 6;
        const float* w0 = W + (size_t)(2 * p) * OUT_SIZE + h * 16;
        const float* w1 = w0 + OUT_SIZE;
        unsigned* Wt32 = (unsigned*)sm.g.Wt;
        #pragma unroll
        for (int i = 0; i < 16; ++i)
            Wt32[(h * 16 + i) * (WS / 2) + p] = pack2(w0[i], w1[i]);
    }
    __syncthreads();

    // ---------------- phase 0c: GEMM + int8 rowscale quantize ---------------
    {
        const int lane = tid & 63;
        const int wv   = tid >> 6;
        const int quad = lane >> 4;
        const int col  = lane & 15;

        float bcol[4];
        #pragma unroll
        for (int nt = 0; nt < 4; ++nt) bcol[nt] = b[nt * 16 + col];

        union U8 { short8 v; unsigned short u[8]; };
        unsigned* cl = sm.g.Clds[wv];

        for (int tile = (int)blockIdx.x * 4 + wv; tile < N_TILES; tile += G * 4) {
            const int r0 = tile * 16;
            const float* arow = data + (size_t)(r0 + col) * IN_SIZE + quad * 8;

            f32x4 acc[4];
            #pragma unroll
            for (int nt = 0; nt < 4; ++nt) acc[nt] = (f32x4){0.f, 0.f, 0.f, 0.f};

            #pragma unroll
            for (int kc = 0; kc < 4; ++kc) {
                const float4 x0 = *(const float4*)(arow + kc * 32);
                const float4 x1 = *(const float4*)(arow + kc * 32 + 4);
                U8 t;
                t.u[0] = f2bf(x0.x); t.u[1] = f2bf(x0.y);
                t.u[2] = f2bf(x0.z); t.u[3] = f2bf(x0.w);
                t.u[4] = f2bf(x1.x); t.u[5] = f2bf(x1.y);
                t.u[6] = f2bf(x1.z); t.u[7] = f2bf(x1.w);
                // W fragments re-read from LDS per kc (16 VGPR live, not 64):
                #pragma unroll
                for (int nt = 0; nt < 4; ++nt) {
                    const short8 wb = *(const short8*)(
                        sm.g.Wt + (nt * 16 + col) * WS + kc * 32 + quad * 8);
                    acc[nt] = __builtin_amdgcn_mfma_f32_16x16x32_bf16(
                        t.v, wb, acc[nt], 0, 0, 0);
                }
            }

            // epilogue: +bias, per-row absmax, biased-uint8 quantize
            // C/D layout: channel nt*16+col, row quad*4+reg
            float v[4][4];   // [nt][r]
            #pragma unroll
            for (int nt = 0; nt < 4; ++nt)
                #pragma unroll
                for (int r = 0; r < 4; ++r)
                    v[nt][r] = acc[nt][r] + bcol[nt];

            float rmax[4];
            #pragma unroll
            for (int r = 0; r < 4; ++r) {
                float m = fabsf(v[0][r]);
                m = fmaxf(m, fabsf(v[1][r]));
                m = fmaxf(m, fabsf(v[2][r]));
                m = fmaxf(m, fabsf(v[3][r]));
                m = fmaxf(m, __shfl_xor(m, 1, 64));
                m = fmaxf(m, __shfl_xor(m, 2, 64));
                m = fmaxf(m, __shfl_xor(m, 4, 64));
                m = fmaxf(m, __shfl_xor(m, 8, 64));
                rmax[r] = m;
            }
            if (col < 4)
                H0s[r0 + quad * 4 + col] = rmax[col] * (1.f / 127.f);

            #pragma unroll
            for (int r = 0; r < 4; ++r) {
                const float inv = rmax[r] > 0.f ? 127.f / rmax[r] : 0.f;
                const unsigned u0 = (unsigned)(int)rintf(v[0][r] * inv + 128.f);
                const unsigned u1 = (unsigned)(int)rintf(v[1][r] * inv + 128.f);
                const unsigned u2 = (unsigned)(int)rintf(v[2][r] * inv + 128.f);
                const unsigned u3 = (unsigned)(int)rintf(v[3][r] * inv + 128.f);
                cl[(quad * 4 + r) * 20 + col] =
                    u0 | (u1 << 8) | (u2 << 16) | (u3 << 24);
            }

            // transpose readback (wave-private LDS region, no barrier needed)
            {
                const int row = lane >> 2;
                const int seg = lane & 3;
                const uint4 vv = *(const uint4*)(cl + row * 20 + seg * 4);
                H0[(size_t)(r0 + row) * 4 + seg] = vv;
            }
        }
    }

    __threadfence();      // make H0/H0s/rowptr visible across XCDs
    grid.sync();

    // ---------------- phase 1: prop round 1 (requantize) --------------------
    prop_phase<false>(H0, H0s, H1, H1s, nullptr, rowptr, src, sm.T, G);

    __threadfence();      // make H1/H1s visible across XCDs
    grid.sync();

    // ---------------- phase 2: prop round 2 (final, fp32+relu) --------------
    prop_phase<true>(H1, H1s, nullptr, nullptr, out, rowptr, src, sm.T, G);
}

// ---------------------------------------------------------------------------
// Launch: cooperative, grid clamped to queried co-residency.
// ---------------------------------------------------------------------------
extern "C" void kernel_launch(void* const* d_in, const int* in_sizes, int n_in,
                              void* d_out, int out_size, void* d_ws, size_t ws_size,
                              hipStream_t stream)
{
    const float* data = (const float*)d_in[0];
    const float* W    = (const float*)d_in[1];
    const float* b    = (const float*)d_in[2];
    const int*   src  = (const int*)d_in[3];
    const int*   tgt  = (const int*)d_in[4];

    // ws: H0 int8 (6.4MB) | H1 int8 (6.4MB) | H0s | H1s | rowptr
    char*  base   = (char*)d_ws;
    uint4* H0     = (uint4*)base;
    uint4* H1     = (uint4*)(base + (size_t)N_NODES * OUT_SIZE);
    float* H0s    = (float*)(base + 2 * (size_t)N_NODES * OUT_SIZE);
    float* H1s    = H0s + N_NODES;
    int*   rowptr = (int*)(H1s + N_NODES);
    float* out    = (float*)d_out;

    static int g_blocks = 0;
    if (g_blocks == 0) {
        int maxb = 0;
        if (hipOccupancyMaxActiveBlocksPerMultiprocessor(
                &maxb, gcn_fused, 256, 0) != hipSuccess || maxb <= 0)
            maxb = 2;   // conservative fallback: certainly co-resident
        g_blocks = maxb * 256;                 // 256 CUs on MI355X
        if (g_blocks > 2048) g_blocks = 2048;
    }

    void* args[] = {
        (void*)&data, (void*)&W, (void*)&b, (void*)&src, (void*)&tgt,
        (void*)&H0, (void*)&H0s, (void*)&H1, (void*)&H1s,
        (void*)&rowptr, (void*)&out
    };
    hipLaunchCooperativeKernel((const void*)gcn_fused, dim3(g_blocks),
                               dim3(256), args, 0, stream);
}

// Round 9
// 177.716 us; speedup vs baseline: 2.0293x; 2.0293x over previous
//
#include <hip/hip_runtime.h>

#define N_NODES 100000
#define N_EDGES 800000
#define IN_SIZE 128
#define OUT_SIZE 64

#define RP_BLOCKS   ((N_EDGES + 255) / 256)   // 3125 boundary-detect blocks, FIRST
#define GEMM_BLOCKS 1024                      // 4 blocks/CU
#define N_TILES     (N_NODES / 16)            // 6250 exact
#define PROP_BLOCKS ((N_NODES + 63) / 64)     // 64 nodes/block, 4 lanes/node
#define WS 136   // Wt LDS stride in bf16 elements (272B rows, 16B-aligned)

typedef __attribute__((ext_vector_type(8))) short short8;
typedef __attribute__((ext_vector_type(4))) float f32x4;
typedef __attribute__((ext_vector_type(4))) unsigned u32x4;
typedef __attribute__((ext_vector_type(2))) unsigned u32x2;

__device__ __forceinline__ unsigned short f2bf(float x) {
    unsigned u = __float_as_uint(x);
    u += 0x7FFFu + ((u >> 16) & 1u);          // round-to-nearest-even
    return (unsigned short)(u >> 16);
}
__device__ __forceinline__ unsigned pack2(float lo, float hi) {
    return (unsigned)f2bf(lo) | ((unsigned)f2bf(hi) << 16);
}

// R14 layout: H buffers are stored as TWO channel-half PLANES of 32B rows
// (8 dwords). Plane h row = global dwords [8h, 8h+8). dword d, byte b holds
// channel d+16b (d global in [0,16)), stored BIASED (u = q+128).
// Rationale (R13 counters): whole-pipeline HBM = 138MB (3.5% peak) => the
// 40us/round cost is NOT HBM; only consistent model is LLC random-line
// traffic because H (6.4MB) misses the 4MiB per-XCD L2. A 3.2MB plane +
// 0.4MB scales IS L2-resident => gathers become L2 hits. One dispatch per
// (round, half) keeps the working set pure; nt-hints keep streams out of L2.
// R14c fix: FINAL un-permute loop is 2 iterations (512 float4 = 64x32), not
// 8 -- the 8-iter version read T out of bounds (NaN) and raced node writes.

// ---------------------------------------------------------------------------
// Kernel 1 (fused): CSR rowptr + H0 = int8_rowscale(data @ W + b) via MFMA.
// Identical to the 140.5us baseline except the H store targets the planes.
// ---------------------------------------------------------------------------
__global__ __launch_bounds__(256) void gemm_rowptr_kernel(
    const float* __restrict__ data, const float* __restrict__ W,
    const float* __restrict__ b, const int* __restrict__ tgt,
    unsigned* __restrict__ H0a, unsigned* __restrict__ H0b,
    float* __restrict__ Hs, int* __restrict__ rowptr)
{
    if (blockIdx.x < RP_BLOCKS) {
        const int e = (int)blockIdx.x * 256 + (int)threadIdx.x;
        if (e < N_EDGES) {
            const int bb = tgt[e];
            const int a  = (e == 0) ? -1 : tgt[e - 1];
            for (int t = a + 1; t <= bb; ++t) rowptr[t] = e;
            if (e == N_EDGES - 1)
                for (int t = bb + 1; t <= N_NODES; ++t) rowptr[t] = N_EDGES;
        }
        return;
    }

    __shared__ __align__(16) unsigned short Wt[64 * WS];  // 17408 B
    __shared__ unsigned Clds[4][16 * 20];                 //  5120 B

    const int tid  = threadIdx.x;
    const int lane = tid & 63;
    const int wv   = tid >> 6;
    const int quad = lane >> 4;
    const int col  = lane & 15;

    // ---- stage W (fp32 row-major [k][n]) -> LDS bf16 transposed Wt[n][k] ----
    {
        const int p = tid & 63;
        const int h = tid >> 6;
        const float* w0 = W + (size_t)(2 * p) * OUT_SIZE + h * 16;
        const float* w1 = w0 + OUT_SIZE;
        unsigned* Wt32 = (unsigned*)Wt;
        #pragma unroll
        for (int i = 0; i < 16; ++i)
            Wt32[(h * 16 + i) * (WS / 2) + p] = pack2(w0[i], w1[i]);
    }
    __syncthreads();

    float bcol[4];
    #pragma unroll
    for (int nt = 0; nt < 4; ++nt) bcol[nt] = b[nt * 16 + col];

    // ---- W fragments from LDS: one ds_read_b128 each ----
    short8 wb[4][4];
    #pragma unroll
    for (int kc = 0; kc < 4; ++kc)
        #pragma unroll
        for (int nt = 0; nt < 4; ++nt)
            wb[kc][nt] = *(const short8*)(
                Wt + (nt * 16 + col) * WS + kc * 32 + quad * 8);

    union U8 { short8 v; unsigned short u[8]; };
    unsigned* cl = Clds[wv];

    for (int tile = ((int)blockIdx.x - RP_BLOCKS) * 4 + wv; tile < N_TILES;
         tile += GEMM_BLOCKS * 4) {
        const int r0 = tile * 16;
        const float* arow = data + (size_t)(r0 + col) * IN_SIZE + quad * 8;

        short8 af[4];
        #pragma unroll
        for (int kc = 0; kc < 4; ++kc) {
            const float4 x0 = *(const float4*)(arow + kc * 32);
            const float4 x1 = *(const float4*)(arow + kc * 32 + 4);
            U8 t;
            t.u[0] = f2bf(x0.x); t.u[1] = f2bf(x0.y);
            t.u[2] = f2bf(x0.z); t.u[3] = f2bf(x0.w);
            t.u[4] = f2bf(x1.x); t.u[5] = f2bf(x1.y);
            t.u[6] = f2bf(x1.z); t.u[7] = f2bf(x1.w);
            af[kc] = t.v;
        }

        f32x4 acc[4];
        #pragma unroll
        for (int nt = 0; nt < 4; ++nt) acc[nt] = (f32x4){0.f, 0.f, 0.f, 0.f};
        #pragma unroll
        for (int kc = 0; kc < 4; ++kc) {
            #pragma unroll
            for (int nt = 0; nt < 4; ++nt)
                acc[nt] = __builtin_amdgcn_mfma_f32_16x16x32_bf16(
                    af[kc], wb[kc][nt], acc[nt], 0, 0, 0);
        }

        // epilogue: +bias, per-row absmax, biased-uint8 quantize
        // C/D layout: channel nt*16+col, row quad*4+reg
        float v[4][4];   // [nt][r]
        #pragma unroll
        for (int nt = 0; nt < 4; ++nt)
            #pragma unroll
            for (int r = 0; r < 4; ++r)
                v[nt][r] = acc[nt][r] + bcol[nt];

        float rmax[4];
        #pragma unroll
        for (int r = 0; r < 4; ++r) {
            float m = fabsf(v[0][r]);
            m = fmaxf(m, fabsf(v[1][r]));
            m = fmaxf(m, fabsf(v[2][r]));
            m = fmaxf(m, fabsf(v[3][r]));
            m = fmaxf(m, __shfl_xor(m, 1, 64));
            m = fmaxf(m, __shfl_xor(m, 2, 64));
            m = fmaxf(m, __shfl_xor(m, 4, 64));
            m = fmaxf(m, __shfl_xor(m, 8, 64));
            rmax[r] = m;
        }
        if (col < 4)
            Hs[r0 + quad * 4 + col] = rmax[col] * (1.f / 127.f);

        #pragma unroll
        for (int r = 0; r < 4; ++r) {
            const float inv = rmax[r] > 0.f ? 127.f / rmax[r] : 0.f;
            const unsigned u0 = (unsigned)(int)rintf(v[0][r] * inv + 128.f);
            const unsigned u1 = (unsigned)(int)rintf(v[1][r] * inv + 128.f);
            const unsigned u2 = (unsigned)(int)rintf(v[2][r] * inv + 128.f);
            const unsigned u3 = (unsigned)(int)rintf(v[3][r] * inv + 128.f);
            cl[(quad * 4 + r) * 20 + col] =
                u0 | (u1 << 8) | (u2 << 16) | (u3 << 24);
        }

        // transpose readback -> plane stores (nt: consumed 2 dispatches later)
        {
            const int row = lane >> 2;
            const int seg = lane & 3;
            const u32x4 vv = *(const u32x4*)(cl + row * 20 + seg * 4);
            unsigned* pl = (seg & 2) ? H0b : H0a;
            __builtin_nontemporal_store(vv,
                (u32x4*)(pl + (size_t)(r0 + row) * 8 + (seg & 1) * 4));
        }
    }
}

// ---------------------------------------------------------------------------
// Kernel 2..5: one propagation round on ONE 32-channel half-plane.
// Working set per dispatch: in-plane 3.2MB + insc 0.4MB -> L2-resident/XCD.
// Streams (src reads, quantized/final writes) use nontemporal hints so they
// don't evict the gather set. No launch_bounds cap: R12/R13 showed VGPR
// pressure serializes the 8-deep gather pipeline (MLP is the resource).
// ---------------------------------------------------------------------------
#define ACC8(vv, c)                                                         \
    {                                                                        \
        const unsigned _wx = (vv).x, _wy = (vv).y;                           \
        _Pragma("unroll")                                                    \
        for (int _b = 0; _b < 4; ++_b) {                                     \
            acc[_b]     = fmaf((float)((_wx >> (8 * _b)) & 255u), (c),       \
                               acc[_b]);                                     \
            acc[4 + _b] = fmaf((float)((_wy >> (8 * _b)) & 255u), (c),       \
                               acc[4 + _b]);                                 \
        }                                                                    \
    }

template <bool FINAL>
__global__ __launch_bounds__(256) void prop_half_kernel(
    const uint2* __restrict__ inq,    // half plane: 4 uint2 per node
    const float* __restrict__ insc,
    unsigned* __restrict__ outq, float* __restrict__ outsc,
    float* __restrict__ out, int choff,   // 8*h (FINAL channel offset)
    const int* __restrict__ rowptr, const int* __restrict__ src)
{
    const int tid   = threadIdx.x;
    const int lane  = tid & 63;
    const int s     = lane & 3;     // 8B chunk: plane dwords {2s, 2s+1}
    const int lbase = lane & 60;    // subgroup base lane
    const int noder = blockIdx.x * 64 + (tid >> 2);
    const bool valid = noder < N_NODES;
    const int node  = valid ? noder : N_NODES - 1;

    const int start = rowptr[node];
    const int end   = rowptr[node + 1];
    const int deg   = end - start;

    float acc[8];
    #pragma unroll
    for (int k = 0; k < 8; ++k) acc[k] = 0.f;
    float sumS = 0.f;

    if (deg > 0) {
        {   // own contribution first: ownq/owns die before the edge loop
            const uint2 ownq = inq[(size_t)node * 4 + s];
            const float owns = insc[node];
            ACC8(ownq, owns);
            sumS = owns;
        }
        for (int base = start; base < end; base += 8) {
            const int rem = end - base;
            const int liA = base + s;
            const int svA = __builtin_nontemporal_load(
                &src[liA < end ? liA : base]);
            int svB = 0;
            if (base + 4 < end) {
                const int liB = base + 4 + s;
                svB = __builtin_nontemporal_load(
                    &src[liB < end ? liB : base + 4]);
            }
            const int e0 = __shfl(svA, lbase + 0, 64);
            const int e1 = __shfl(svA, lbase + 1, 64);
            const int e2 = __shfl(svA, lbase + 2, 64);
            const int e3 = __shfl(svA, lbase + 3, 64);
            const int e4 = __shfl(svB, lbase + 0, 64);
            const int e5 = __shfl(svB, lbase + 1, 64);
            const int e6 = __shfl(svB, lbase + 2, 64);
            const int e7 = __shfl(svB, lbase + 3, 64);

            const int i1 = rem > 1 ? e1 : e0;
            const int i2 = rem > 2 ? e2 : e0;
            const int i3 = rem > 3 ? e3 : e0;
            const int i4 = rem > 4 ? e4 : e0;
            const int i5 = rem > 5 ? e5 : e0;
            const int i6 = rem > 6 ? e6 : e0;
            const int i7 = rem > 7 ? e7 : e0;

            const uint2 v0 = inq[(size_t)e0 * 4 + s];
            const uint2 v1 = inq[(size_t)i1 * 4 + s];
            const uint2 v2 = inq[(size_t)i2 * 4 + s];
            const uint2 v3 = inq[(size_t)i3 * 4 + s];
            const uint2 v4 = inq[(size_t)i4 * 4 + s];
            const uint2 v5 = inq[(size_t)i5 * 4 + s];
            const uint2 v6 = inq[(size_t)i6 * 4 + s];
            const uint2 v7 = inq[(size_t)i7 * 4 + s];

            const float c0 = insc[e0];
            const float c1 = rem > 1 ? insc[i1] : 0.f;
            const float c2 = rem > 2 ? insc[i2] : 0.f;
            const float c3 = rem > 3 ? insc[i3] : 0.f;
            const float c4 = rem > 4 ? insc[i4] : 0.f;
            const float c5 = rem > 5 ? insc[i5] : 0.f;
            const float c6 = rem > 6 ? insc[i6] : 0.f;
            const float c7 = rem > 7 ? insc[i7] : 0.f;

            sumS += (c0 + c1) + (c2 + c3) + ((c4 + c5) + (c6 + c7));
            ACC8(v0, c0); ACC8(v1, c1); ACC8(v2, c2); ACC8(v3, c3);
            ACC8(v4, c4); ACC8(v5, c5); ACC8(v6, c6); ACC8(v7, c7);
        }
    }

    float val[8];
    if (deg == 0) {
        #pragma unroll
        for (int k = 0; k < 8; ++k) val[k] = 0.f;
    } else {
        const float invm  = 1.0f / (float)(deg + 1);
        const float bias  = 128.f * sumS;
        #pragma unroll
        for (int k = 0; k < 8; ++k) {
            val[k] = (acc[k] - bias) * invm;
            if (FINAL) val[k] = fmaxf(val[k], 0.f);
        }
    }

    if (FINAL) {
        // un-permute: val[j*4+b] is plane dword k=2s+j, byte b
        //   -> channel (k + choff) + 16*b ; compact LDS index k + 8*b
        __shared__ __align__(16) float T[64 * 36];   // 9216 B
        const int nl = tid >> 2;
        #pragma unroll
        for (int j = 0; j < 2; ++j)
            #pragma unroll
            for (int bb = 0; bb < 4; ++bb)
                T[nl * 36 + (2 * s + j) + 8 * bb] = val[j * 4 + bb];
        __syncthreads();
        const int nb = blockIdx.x * 64;
        // 64 nodes x 32 channels = 512 float4 -> exactly 2 iterations of 256
        #pragma unroll
        for (int p = 0; p < 2; ++p) {
            const int f4 = p * 256 + tid;    // float4 index in 64x32 tile
            const int n  = f4 >> 3;          // 8 float4 per node
            const int q  = f4 & 7;           // compact chunk: k=4(q&1), b=q>>1
            if (nb + n < N_NODES) {
                const f32x4 vv = *(const f32x4*)(T + n * 36 + q * 4);
                const int ch = 4 * (q & 1) + choff + 16 * (q >> 1);
                __builtin_nontemporal_store(vv,
                    (f32x4*)(out + (size_t)(nb + n) * OUT_SIZE + ch));
            }
        }
    } else {
        // requantize: half-row absmax across 8 in-lane + 4-lane subgroup
        float m = 0.f;
        #pragma unroll
        for (int k = 0; k < 8; ++k) m = fmaxf(m, fabsf(val[k]));
        m = fmaxf(m, __shfl_xor(m, 1, 64));
        m = fmaxf(m, __shfl_xor(m, 2, 64));
        const float invq = m > 0.f ? 127.f / m : 0.f;
        u32x2 pv;
        {
            const unsigned a0 = (unsigned)(int)rintf(val[0] * invq + 128.f);
            const unsigned a1 = (unsigned)(int)rintf(val[1] * invq + 128.f);
            const unsigned a2 = (unsigned)(int)rintf(val[2] * invq + 128.f);
            const unsigned a3 = (unsigned)(int)rintf(val[3] * invq + 128.f);
            pv.x = a0 | (a1 << 8) | (a2 << 16) | (a3 << 24);
            const unsigned b0 = (unsigned)(int)rintf(val[4] * invq + 128.f);
            const unsigned b1 = (unsigned)(int)rintf(val[5] * invq + 128.f);
            const unsigned b2 = (unsigned)(int)rintf(val[6] * invq + 128.f);
            const unsigned b3 = (unsigned)(int)rintf(val[7] * invq + 128.f);
            pv.y = b0 | (b1 << 8) | (b2 << 16) | (b3 << 24);
        }
        if (valid) {
            __builtin_nontemporal_store(pv,
                (u32x2*)(outq + (size_t)node * 8 + s * 2));
            if (s == 0) outsc[node] = m * (1.f / 127.f);
        }
    }
}

// ---------------------------------------------------------------------------
// Launch: gemm+rowptr, then one dispatch per (round, channel-half).
// ---------------------------------------------------------------------------
extern "C" void kernel_launch(void* const* d_in, const int* in_sizes, int n_in,
                              void* d_out, int out_size, void* d_ws, size_t ws_size,
                              hipStream_t stream)
{
    const float* data = (const float*)d_in[0];
    const float* W    = (const float*)d_in[1];
    const float* b    = (const float*)d_in[2];
    const int*   src  = (const int*)d_in[3];
    const int*   tgt  = (const int*)d_in[4];

    // ws: H0a|H0b|H1a|H1b planes (3.2MB each) | H0s | H1s0 | H1s1 | rowptr
    unsigned* H0a = (unsigned*)d_ws;
    unsigned* H0b = H0a + (size_t)N_NODES * 8;
    unsigned* H1a = H0b + (size_t)N_NODES * 8;
    unsigned* H1b = H1a + (size_t)N_NODES * 8;
    float* H0s    = (float*)(H1b + (size_t)N_NODES * 8);
    float* H1s0   = H0s + N_NODES;
    float* H1s1   = H1s0 + N_NODES;
    int*   rowptr = (int*)(H1s1 + N_NODES);
    float* out    = (float*)d_out;

    gemm_rowptr_kernel<<<RP_BLOCKS + GEMM_BLOCKS, 256, 0, stream>>>(
        data, W, b, tgt, H0a, H0b, H0s, rowptr);

    prop_half_kernel<false><<<PROP_BLOCKS, 256, 0, stream>>>(
        (const uint2*)H0a, H0s, H1a, H1s0, nullptr, 0, rowptr, src);
    prop_half_kernel<false><<<PROP_BLOCKS, 256, 0, stream>>>(
        (const uint2*)H0b, H0s, H1b, H1s1, nullptr, 8, rowptr, src);

    prop_half_kernel<true><<<PROP_BLOCKS, 256, 0, stream>>>(
        (const uint2*)H1a, H1s0, nullptr, nullptr, out, 0, rowptr, src);
    prop_half_kernel<true><<<PROP_BLOCKS, 256, 0, stream>>>(
        (const uint2*)H1b, H1s1, nullptr, nullptr, out, 8, rowptr, src);
}

// Round 11
// 141.991 us; speedup vs baseline: 2.5399x; 1.2516x over previous
//
#include <hip/hip_runtime.h>

#define N_NODES 100000
#define N_EDGES 800000
#define IN_SIZE 128
#define OUT_SIZE 64

#define RP_BLOCKS   ((N_EDGES + 255) / 256)   // 3125 boundary-detect blocks, FIRST
#define GEMM_BLOCKS 1024                      // 4 blocks/CU
#define N_TILES     (N_NODES / 16)            // 6250 exact
#define PROP_BLOCKS ((N_NODES + 63) / 64)     // 64 nodes/block, 4 lanes/node
#define WS 136   // Wt LDS stride in bf16 elements (272B rows, 16B-aligned)

typedef __attribute__((ext_vector_type(8))) short short8;
typedef __attribute__((ext_vector_type(4))) float f32x4;

__device__ __forceinline__ unsigned short f2bf(float x) {
    unsigned u = __float_as_uint(x);
    u += 0x7FFFu + ((u >> 16) & 1u);          // round-to-nearest-even
    return (unsigned short)(u >> 16);
}
__device__ __forceinline__ unsigned pack2(float lo, float hi) {
    return (unsigned)f2bf(lo) | ((unsigned)f2bf(hi) << 16);
}

// int8 row layout (both H buffers): row = 16 dwords; dword d's byte b holds
// channel (d + 16*b), stored BIASED (u = q + 128). Per-row fp32 dequant
// scale in a separate array: val = scale * (u - 128).
//
// R15: exact revert to the proven 140.5us R0 configuration. Experiment ledger
// (all within-session, all measured): occupancy cap (256,6) = +6us; coop
// 1-dispatch fusion = +220us (compiler cut VGPR to 56, serialized the gather
// pipeline); channel-half planes = +37us (line COUNT is invariant: a 32B-row
// gather fetches the same 128B line; 2x dispatches = 2x line traffic).
// Structural constraint: 2 dependent rounds x 800K random 64B-row gathers
// from 6.4MB (> 4MiB per-XCD L2) = ~102MB/round LLC line traffic at ~2.6TB/s
// realized (75% of random-line ceiling) = ~40us/round floor in this
// decomposition.

// ---------------------------------------------------------------------------
// Kernel 1 (fused): CSR rowptr (boundary-detect scatter, blocks FIRST) +
// H0 = int8_rowscale(data @ W + b) via MFMA.
// ---------------------------------------------------------------------------
__global__ __launch_bounds__(256) void gemm_rowptr_kernel(
    const float* __restrict__ data, const float* __restrict__ W,
    const float* __restrict__ b, const int* __restrict__ tgt,
    uint4* __restrict__ H, float* __restrict__ Hs, int* __restrict__ rowptr)
{
    if (blockIdx.x < RP_BLOCKS) {
        const int e = (int)blockIdx.x * 256 + (int)threadIdx.x;
        if (e < N_EDGES) {
            const int bb = tgt[e];
            const int a  = (e == 0) ? -1 : tgt[e - 1];
            for (int t = a + 1; t <= bb; ++t) rowptr[t] = e;
            if (e == N_EDGES - 1)
                for (int t = bb + 1; t <= N_NODES; ++t) rowptr[t] = N_EDGES;
        }
        return;
    }

    __shared__ __align__(16) unsigned short Wt[64 * WS];  // 17408 B
    __shared__ unsigned Clds[4][16 * 20];                 //  5120 B

    const int tid  = threadIdx.x;
    const int lane = tid & 63;
    const int wv   = tid >> 6;
    const int quad = lane >> 4;
    const int col  = lane & 15;

    // ---- stage W (fp32 row-major [k][n]) -> LDS bf16 transposed Wt[n][k] ----
    {
        const int p = tid & 63;
        const int h = tid >> 6;
        const float* w0 = W + (size_t)(2 * p) * OUT_SIZE + h * 16;
        const float* w1 = w0 + OUT_SIZE;
        unsigned* Wt32 = (unsigned*)Wt;
        #pragma unroll
        for (int i = 0; i < 16; ++i)
            Wt32[(h * 16 + i) * (WS / 2) + p] = pack2(w0[i], w1[i]);
    }
    __syncthreads();

    float bcol[4];
    #pragma unroll
    for (int nt = 0; nt < 4; ++nt) bcol[nt] = b[nt * 16 + col];

    // ---- W fragments from LDS: one ds_read_b128 each ----
    short8 wb[4][4];
    #pragma unroll
    for (int kc = 0; kc < 4; ++kc)
        #pragma unroll
        for (int nt = 0; nt < 4; ++nt)
            wb[kc][nt] = *(const short8*)(
                Wt + (nt * 16 + col) * WS + kc * 32 + quad * 8);

    union U8 { short8 v; unsigned short u[8]; };
    unsigned* cl = Clds[wv];

    for (int tile = ((int)blockIdx.x - RP_BLOCKS) * 4 + wv; tile < N_TILES;
         tile += GEMM_BLOCKS * 4) {
        const int r0 = tile * 16;
        const float* arow = data + (size_t)(r0 + col) * IN_SIZE + quad * 8;

        short8 af[4];
        #pragma unroll
        for (int kc = 0; kc < 4; ++kc) {
            const float4 x0 = *(const float4*)(arow + kc * 32);
            const float4 x1 = *(const float4*)(arow + kc * 32 + 4);
            U8 t;
            t.u[0] = f2bf(x0.x); t.u[1] = f2bf(x0.y);
            t.u[2] = f2bf(x0.z); t.u[3] = f2bf(x0.w);
            t.u[4] = f2bf(x1.x); t.u[5] = f2bf(x1.y);
            t.u[6] = f2bf(x1.z); t.u[7] = f2bf(x1.w);
            af[kc] = t.v;
        }

        f32x4 acc[4];
        #pragma unroll
        for (int nt = 0; nt < 4; ++nt) acc[nt] = (f32x4){0.f, 0.f, 0.f, 0.f};
        #pragma unroll
        for (int kc = 0; kc < 4; ++kc) {
            #pragma unroll
            for (int nt = 0; nt < 4; ++nt)
                acc[nt] = __builtin_amdgcn_mfma_f32_16x16x32_bf16(
                    af[kc], wb[kc][nt], acc[nt], 0, 0, 0);
        }

        // epilogue: +bias, per-row absmax, biased-uint8 quantize
        // C/D layout: channel nt*16+col, row quad*4+reg
        float v[4][4];   // [nt][r]
        #pragma unroll
        for (int nt = 0; nt < 4; ++nt)
            #pragma unroll
            for (int r = 0; r < 4; ++r)
                v[nt][r] = acc[nt][r] + bcol[nt];

        float rmax[4];
        #pragma unroll
        for (int r = 0; r < 4; ++r) {
            float m = fabsf(v[0][r]);
            m = fmaxf(m, fabsf(v[1][r]));
            m = fmaxf(m, fabsf(v[2][r]));
            m = fmaxf(m, fabsf(v[3][r]));
            m = fmaxf(m, __shfl_xor(m, 1, 64));
            m = fmaxf(m, __shfl_xor(m, 2, 64));
            m = fmaxf(m, __shfl_xor(m, 4, 64));
            m = fmaxf(m, __shfl_xor(m, 8, 64));
            rmax[r] = m;
        }
        if (col < 4)
            Hs[r0 + quad * 4 + col] = rmax[col] * (1.f / 127.f);

        #pragma unroll
        for (int r = 0; r < 4; ++r) {
            const float inv = rmax[r] > 0.f ? 127.f / rmax[r] : 0.f;
            const unsigned u0 = (unsigned)(int)rintf(v[0][r] * inv + 128.f);
            const unsigned u1 = (unsigned)(int)rintf(v[1][r] * inv + 128.f);
            const unsigned u2 = (unsigned)(int)rintf(v[2][r] * inv + 128.f);
            const unsigned u3 = (unsigned)(int)rintf(v[3][r] * inv + 128.f);
            cl[(quad * 4 + r) * 20 + col] =
                u0 | (u1 << 8) | (u2 << 16) | (u3 << 24);
        }

        // transpose readback (wave-private LDS region, no barrier needed):
        // 64B row stores
        {
            const int row = lane >> 2;
            const int seg = lane & 3;
            const uint4 vv = *(const uint4*)(cl + row * 20 + seg * 4);
            H[(size_t)(r0 + row) * 4 + seg] = vv;
        }
    }
}

// ---------------------------------------------------------------------------
// Kernel 2/3: one propagation round on int8 per-row-scale rows (64B/row).
// At the LLC random-line floor: 800K edges x one 128B line each ~ 102MB
// line traffic/round; measured ~2.6TB/s realized (75% of ceiling).
// ---------------------------------------------------------------------------
#define ACC16(vv, c)                                                        \
    {                                                                        \
        const unsigned* _w = (const unsigned*)&(vv);                         \
        _Pragma("unroll")                                                    \
        for (int _d = 0; _d < 4; ++_d) {                                     \
            _Pragma("unroll")                                                \
            for (int _b = 0; _b < 4; ++_b)                                   \
                acc[_d * 4 + _b] = fmaf(                                     \
                    (float)((_w[_d] >> (8 * _b)) & 255u), (c), acc[_d*4+_b]);\
        }                                                                    \
    }

template <bool FINAL>
__global__ __launch_bounds__(256) void prop_kernel(
    const uint4* __restrict__ inq, const float* __restrict__ insc,
    void* __restrict__ outp, float* __restrict__ outsc,
    const int* __restrict__ rowptr, const int* __restrict__ src)
{
    const int tid   = threadIdx.x;
    const int lane  = tid & 63;
    const int s     = lane & 3;     // 16B chunk (dwords s*4..s*4+3)
    const int lbase = lane & 60;    // subgroup base lane
    const int noder = blockIdx.x * 64 + (tid >> 2);
    const bool valid = noder < N_NODES;
    const int node  = valid ? noder : N_NODES - 1;

    const int start = rowptr[node];
    const int end   = rowptr[node + 1];
    const int deg   = end - start;

    const uint4 ownq = inq[(size_t)node * 4 + s];
    const float owns = insc[node];

    float acc[16];
    #pragma unroll
    for (int k = 0; k < 16; ++k) acc[k] = 0.f;
    float sumS = 0.f;

    if (deg > 0) {
        for (int base = start; base < end; base += 8) {
            const int rem = end - base;
            const int liA = base + s;
            const int svA = src[liA < end ? liA : base];
            int svB = 0;
            if (base + 4 < end) {
                const int liB = base + 4 + s;
                svB = src[liB < end ? liB : base + 4];
            }
            const int e0 = __shfl(svA, lbase + 0, 64);
            const int e1 = __shfl(svA, lbase + 1, 64);
            const int e2 = __shfl(svA, lbase + 2, 64);
            const int e3 = __shfl(svA, lbase + 3, 64);
            const int e4 = __shfl(svB, lbase + 0, 64);
            const int e5 = __shfl(svB, lbase + 1, 64);
            const int e6 = __shfl(svB, lbase + 2, 64);
            const int e7 = __shfl(svB, lbase + 3, 64);

            const int i1 = rem > 1 ? e1 : e0;
            const int i2 = rem > 2 ? e2 : e0;
            const int i3 = rem > 3 ? e3 : e0;
            const int i4 = rem > 4 ? e4 : e0;
            const int i5 = rem > 5 ? e5 : e0;
            const int i6 = rem > 6 ? e6 : e0;
            const int i7 = rem > 7 ? e7 : e0;

            const uint4 v0 = inq[(size_t)e0 * 4 + s];
            const uint4 v1 = inq[(size_t)i1 * 4 + s];
            const uint4 v2 = inq[(size_t)i2 * 4 + s];
            const uint4 v3 = inq[(size_t)i3 * 4 + s];
            const uint4 v4 = inq[(size_t)i4 * 4 + s];
            const uint4 v5 = inq[(size_t)i5 * 4 + s];
            const uint4 v6 = inq[(size_t)i6 * 4 + s];
            const uint4 v7 = inq[(size_t)i7 * 4 + s];

            const float c0 = insc[e0];
            const float c1 = rem > 1 ? insc[i1] : 0.f;
            const float c2 = rem > 2 ? insc[i2] : 0.f;
            const float c3 = rem > 3 ? insc[i3] : 0.f;
            const float c4 = rem > 4 ? insc[i4] : 0.f;
            const float c5 = rem > 5 ? insc[i5] : 0.f;
            const float c6 = rem > 6 ? insc[i6] : 0.f;
            const float c7 = rem > 7 ? insc[i7] : 0.f;

            sumS += c0 + c1 + c2 + c3 + c4 + c5 + c6 + c7;
            ACC16(v0, c0); ACC16(v1, c1); ACC16(v2, c2); ACC16(v3, c3);
            ACC16(v4, c4); ACC16(v5, c5); ACC16(v6, c6); ACC16(v7, c7);
        }
        // own contribution
        ACC16(ownq, owns);
        sumS += owns;
    }

    float val[16];
    if (deg == 0) {
        #pragma unroll
        for (int k = 0; k < 16; ++k) val[k] = 0.f;
    } else {
        const float invm  = 1.0f / (float)(deg + 1);
        const float bias  = 128.f * sumS;
        #pragma unroll
        for (int k = 0; k < 16; ++k) {
            val[k] = (acc[k] - bias) * invm;
            if (FINAL) val[k] = fmaxf(val[k], 0.f);
        }
    }

    if (FINAL) {
        // un-permute: channel of val[d*4+b] is (s*4+d) + 16*b
        __shared__ float T[64 * 68];
        const int nl = tid >> 2;
        #pragma unroll
        for (int d = 0; d < 4; ++d)
            #pragma unroll
            for (int bb = 0; bb < 4; ++bb)
                T[nl * 68 + (s * 4 + d) + 16 * bb] = val[d * 4 + bb];
        __syncthreads();
        float* out = (float*)outp;
        const int nb = blockIdx.x * 64;
        #pragma unroll
        for (int p = 0; p < 4; ++p) {
            const int pos = p * 1024 + tid * 4;  // dword index in 64x64 tile
            const int n   = pos >> 6;
            const int ch  = pos & 63;
            if (nb + n < N_NODES) {
                const float4 vv = *(const float4*)(T + n * 68 + ch);
                *(float4*)(out + (size_t)(nb + n) * OUT_SIZE + ch) = vv;
            }
        }
    } else {
        // requantize: row absmax across 16 in-lane + 4-lane subgroup
        float m = 0.f;
        #pragma unroll
        for (int k = 0; k < 16; ++k) m = fmaxf(m, fabsf(val[k]));
        m = fmaxf(m, __shfl_xor(m, 1, 64));
        m = fmaxf(m, __shfl_xor(m, 2, 64));
        const float invq = m > 0.f ? 127.f / m : 0.f;
        uint4 pv;
        unsigned* pw = (unsigned*)&pv;
        #pragma unroll
        for (int d = 0; d < 4; ++d) {
            const unsigned u0 = (unsigned)(int)rintf(val[d * 4 + 0] * invq + 128.f);
            const unsigned u1 = (unsigned)(int)rintf(val[d * 4 + 1] * invq + 128.f);
            const unsigned u2 = (unsigned)(int)rintf(val[d * 4 + 2] * invq + 128.f);
            const unsigned u3 = (unsigned)(int)rintf(val[d * 4 + 3] * invq + 128.f);
            pw[d] = u0 | (u1 << 8) | (u2 << 16) | (u3 << 24);
        }
        if (valid) {
            ((uint4*)outp)[(size_t)node * 4 + s] = pv;
            if (s == 0) outsc[node] = m * (1.f / 127.f);
        }
    }
}

// ---------------------------------------------------------------------------
// Launch
// ---------------------------------------------------------------------------
extern "C" void kernel_launch(void* const* d_in, const int* in_sizes, int n_in,
                              void* d_out, int out_size, void* d_ws, size_t ws_size,
                              hipStream_t stream)
{
    const float* data = (const float*)d_in[0];
    const float* W    = (const float*)d_in[1];
    const float* b    = (const float*)d_in[2];
    const int*   src  = (const int*)d_in[3];
    const int*   tgt  = (const int*)d_in[4];

    // ws: H0 int8 (6.4MB) | H1 int8 (6.4MB) | H0s | H1s | rowptr
    char*  base   = (char*)d_ws;
    uint4* H0     = (uint4*)base;
    uint4* H1     = (uint4*)(base + (size_t)N_NODES * OUT_SIZE);
    float* H0s    = (float*)(base + 2 * (size_t)N_NODES * OUT_SIZE);
    float* H1s    = H0s + N_NODES;
    int*   rowptr = (int*)(H1s + N_NODES);

    gemm_rowptr_kernel<<<RP_BLOCKS + GEMM_BLOCKS, 256, 0, stream>>>(
        data, W, b, tgt, H0, H0s, rowptr);
    prop_kernel<false><<<PROP_BLOCKS, 256, 0, stream>>>(
        H0, H0s, (void*)H1, H1s, rowptr, src);
    prop_kernel<true ><<<PROP_BLOCKS, 256, 0, stream>>>(
        H1, H1s, d_out, nullptr, rowptr, src);
}